// Round 3
// baseline (991.700 us; speedup 1.0000x reference)
//
#include <hip/hip_runtime.h>
#include <hip/hip_bf16.h>

// Problem constants
#define B_ 4
#define S_ 2048
#define E_ 2048
#define H_ 16
#define D_ 128
#define M_ (B_*S_)   // 8192 rows

typedef __attribute__((ext_vector_type(8))) short short8;
typedef __attribute__((ext_vector_type(4))) float f32x4;

__device__ __forceinline__ unsigned short f2bf(float f) {
  union { __hip_bfloat16 h; unsigned short u; } c;
  c.h = __float2bfloat16(f);
  return c.u;
}

__device__ __forceinline__ void gld_lds16(const void* g, void* l) {
  __builtin_amdgcn_global_load_lds((const __attribute__((address_space(1))) void*)g,
                                   (__attribute__((address_space(3))) void*)l, 16, 0, 0);
}

// ---------------- fp32 -> bf16 cast (vectorized) ----------------
__global__ __launch_bounds__(256) void cast_bf16_kernel(const float* __restrict__ in,
                                                        unsigned short* __restrict__ out,
                                                        int n4) {
  int i = blockIdx.x * 256 + threadIdx.x;
  if (i >= n4) return;
  float4 v = ((const float4*)in)[i];
  ushort4 o;
  o.x = f2bf(v.x); o.y = f2bf(v.y); o.z = f2bf(v.z); o.w = f2bf(v.w);
  ((ushort4*)out)[i] = o;
}

// ---------------- GEMM: C[M,N] = A[M,K] @ W[N,K]^T + bias ----------------
// m97 structure: 128x128 tile, BK=32, 4 waves (2x2 of 64x64), global_load_lds w16.
template <typename OutT>
__global__ __launch_bounds__(256) void gemm_bt(const unsigned short* __restrict__ A,
                                               const unsigned short* __restrict__ W,
                                               const float* __restrict__ bias,
                                               OutT* __restrict__ C,
                                               int M, int N, int K) {
  __shared__ unsigned short As[128 * 32];
  __shared__ unsigned short Bs[128 * 32];
  const int tid  = threadIdx.x;
  const int lane = tid & 63;
  const int wid  = tid >> 6;
  const int m0 = blockIdx.y * 128;
  const int n0 = blockIdx.x * 128;
  const int wr = (wid >> 1) * 64;   // wave row offset in tile
  const int wc = (wid & 1) * 64;    // wave col offset in tile
  const int lr  = lane & 15;
  const int lk8 = (lane >> 4) * 8;

  f32x4 acc[4][4];
#pragma unroll
  for (int i = 0; i < 4; i++)
#pragma unroll
    for (int j = 0; j < 4; j++) acc[i][j] = (f32x4){0.f, 0.f, 0.f, 0.f};

  // staging: tile is 128 rows x 32 cols bf16 = 8192 B; 256 thr x 16 B = 4096 B/pass
  const int o0 = tid * 16;            // byte offset in tile, pass 0
  const int row0 = o0 >> 6, colb0 = o0 & 63;
  const int o1 = o0 + 4096;           // pass 1
  const int row1 = o1 >> 6, colb1 = o1 & 63;
  const int ldsb0 = wid * 1024;       // wave-uniform LDS byte base, pass 0
  const int ldsb1 = wid * 1024 + 4096;

  for (int kt = 0; kt < K; kt += 32) {
    gld_lds16(A + (size_t)(m0 + row0) * K + kt + (colb0 >> 1), (char*)As + ldsb0);
    gld_lds16(A + (size_t)(m0 + row1) * K + kt + (colb1 >> 1), (char*)As + ldsb1);
    gld_lds16(W + (size_t)(n0 + row0) * K + kt + (colb0 >> 1), (char*)Bs + ldsb0);
    gld_lds16(W + (size_t)(n0 + row1) * K + kt + (colb1 >> 1), (char*)Bs + ldsb1);
    __syncthreads();

    short8 af[4], bf[4];
#pragma unroll
    for (int i = 0; i < 4; i++) af[i] = *(const short8*)&As[(wr + i * 16 + lr) * 32 + lk8];
#pragma unroll
    for (int j = 0; j < 4; j++) bf[j] = *(const short8*)&Bs[(wc + j * 16 + lr) * 32 + lk8];
#pragma unroll
    for (int i = 0; i < 4; i++)
#pragma unroll
      for (int j = 0; j < 4; j++)
        acc[i][j] = __builtin_amdgcn_mfma_f32_16x16x32_bf16(af[i], bf[j], acc[i][j], 0, 0, 0);
    __syncthreads();
  }

  // epilogue: C/D layout col=lane&15, row=(lane>>4)*4+r  [m89-verified]
#pragma unroll
  for (int i = 0; i < 4; i++) {
    const int gm = m0 + wr + i * 16 + (lane >> 4) * 4;
#pragma unroll
    for (int j = 0; j < 4; j++) {
      const int gn = n0 + wc + j * 16 + lr;
      const float bv = bias[gn];
#pragma unroll
      for (int r = 0; r < 4; r++) {
        const float v = acc[i][j][r] + bv;
        if constexpr (sizeof(OutT) == 2)
          ((unsigned short*)C)[(size_t)(gm + r) * N + gn] = f2bf(v);
        else
          ((float*)C)[(size_t)(gm + r) * N + gn] = v;
      }
    }
  }
}

// ---------------- causal flash attention ----------------
// 4 waves (256 thr) per block; each wave owns 16 consecutive query rows
// (64-row q-tile per block). KV steps of 32, DOUBLE-BUFFERED in LDS,
// ONE barrier per step:
//   barrier -> issue K gld_lds(t+1) + V reg-loads(t+1) -> compute(t)
//           -> ds_write V(t+1) (compiler inserts vmcnt wait) -> loop.
// Buffer safety: all writes in iter t go to buf^1; all reads of buf^1
// completed before iter t's barrier. Barrier's vmcnt(0)+lgkmcnt(0) drain
// guarantees buf fully staged at top of each iter.
//
// K layout (r1-verified): Ks[buf][32][128] bf16, XOR-swizzle cb ^= (row&7)<<4
//   applied on the GLOBAL source address (linear LDS dest, rule 21).
// V layout (r1-verified): Vt[buf][128][32] transposed, chunk-swizzled:
//   idx(d,kv) = d*32 + (((kv>>3) ^ ((d>>1)&3) ^ ((d>>4)&3))<<3) + (kv&7)
// Pl: per-wave P tile; wave-local lgkmcnt(0)+sched_barrier (same-wave data).
// Online softmax with defer-max (T13, THR=8); slow path == r1 exact math.
__global__ __launch_bounds__(256) void flash_attn(const unsigned short* __restrict__ Q,
                                                  const unsigned short* __restrict__ K,
                                                  const unsigned short* __restrict__ V,
                                                  unsigned short* __restrict__ Ctx) {
  __shared__ unsigned short Ks[2 * 32 * 128];   // 16 KB, swizzled K tiles
  __shared__ unsigned short Vt[2 * 128 * 32];   // 16 KB, swizzled V^T tiles
  __shared__ unsigned short Pl[4 * 16 * 32];    // 4 KB, per-wave P tiles

  const int tid  = threadIdx.x;
  const int lane = tid & 63;
  const int wid  = tid >> 6;
  const int lr  = lane & 15;
  const int lg  = lane >> 4;
  const int lk8 = lg * 8;
  const int qblk = blockIdx.x * 64;         // block q-tile base
  const int q0w  = qblk + wid * 16;         // this wave's q rows
  const int h  = blockIdx.y;
  const int b  = blockIdx.z;
  const size_t base = ((size_t)b * S_) * E_ + (size_t)h * D_;
  const unsigned short* __restrict__ Kh = K + base;
  const unsigned short* __restrict__ Vh = V + base;
  unsigned short* Plw = Pl + wid * 512;

  // ---- K staging geometry (per 32x128 tile = 8192 B; 2 passes x 4096 B) ----
  const int oK0 = tid * 16;
  const int rK0 = oK0 >> 8;                 // rows 0..15
  const int cK0 = (oK0 & 255) ^ ((rK0 & 7) << 4);
  const int rK1 = (oK0 + 4096) >> 8;        // rows 16..31
  const int cK1 = (oK0 & 255) ^ ((rK1 & 7) << 4);
  const unsigned short* ksrc0 = Kh + (size_t)rK0 * E_ + (cK0 >> 1);
  const unsigned short* ksrc1 = Kh + (size_t)rK1 * E_ + (cK1 >> 1);
  char* kdst0 = (char*)Ks + wid * 1024;            // + buf*8192
  char* kdst1 = (char*)Ks + 4096 + wid * 1024;

  // ---- V staging geometry (r1-verified): thread loads 16 u16 of one kv row ----
  const int vr  = tid >> 3;                 // kv row 0..31
  const int c16 = (tid & 7) * 16;           // d base 0..112

  // ---- Q fragments: rows q0w+lr, feature k = kk*32 + lk8 .. +8 ----
  short8 qf[4];
#pragma unroll
  for (int kk = 0; kk < 4; kk++)
    qf[kk] = *(const short8*)&Q[base + (size_t)(q0w + lr) * E_ + kk * 32 + lk8];

  f32x4 o[8];
#pragma unroll
  for (int d0 = 0; d0 < 8; d0++) o[d0] = (f32x4){0.f, 0.f, 0.f, 0.f};
  float mrow[4] = {-INFINITY, -INFINITY, -INFINITY, -INFINITY};
  float lsum[4] = {0.f, 0.f, 0.f, 0.f};
  const float scale = 0.08838834764831845f;  // 1/sqrt(128)

  const int nt = (qblk >> 5) + 2;            // (qblk+64)/32 kv steps

  // ---- prologue: stage tile 0 into buf 0 ----
  gld_lds16(ksrc0, kdst0);
  gld_lds16(ksrc1, kdst1);
  {
    short8 vv0 = *(const short8*)&Vh[(size_t)vr * E_ + c16];
    short8 vv1 = *(const short8*)&Vh[(size_t)vr * E_ + c16 + 8];
#pragma unroll
    for (int j = 0; j < 8; j++) {
      const int d = c16 + j;
      const int sw = ((d >> 1) & 3) ^ ((d >> 4) & 3);
      Vt[d * 32 + (((vr >> 3) ^ sw) << 3) + (vr & 7)] = ((const unsigned short*)&vv0)[j];
    }
#pragma unroll
    for (int j = 0; j < 8; j++) {
      const int d = c16 + 8 + j;
      const int sw = ((d >> 1) & 3) ^ ((d >> 4) & 3);
      Vt[d * 32 + (((vr >> 3) ^ sw) << 3) + (vr & 7)] = ((const unsigned short*)&vv1)[j];
    }
  }

  for (int t = 0; t < nt; ++t) {
    const int buf = t & 1;
    const int kbo = buf * 8192;     // Ks byte offset of current buffer
    const int vbo = buf * 4096;     // Vt element offset of current buffer
    __syncthreads();   // vmcnt+lgkm drain: buf fully staged; buf^1 reads done

    // ---- issue next-tile staging (lands/written during compute) ----
    const bool havenext = (t + 1 < nt);
    short8 nv0, nv1;
    if (havenext) {
      const size_t koff = (size_t)(t + 1) * 32 * E_;
      const int nkbo = kbo ^ 8192;
      gld_lds16(ksrc0 + koff, kdst0 + nkbo);
      gld_lds16(ksrc1 + koff, kdst1 + nkbo);
      nv0 = *(const short8*)&Vh[koff + (size_t)vr * E_ + c16];
      nv1 = *(const short8*)&Vh[koff + (size_t)vr * E_ + c16 + 8];
    }

    const int kv0 = t * 32;
    if (kv0 < q0w + 16) {    // wave has unmasked kv cols this step
      // ---- S = Q K^T for two 16-col chunks (K from swizzled LDS) ----
      f32x4 s0 = (f32x4){0.f, 0.f, 0.f, 0.f};
      f32x4 s1 = (f32x4){0.f, 0.f, 0.f, 0.f};
      const int swK = (lr & 7) << 4;
      const char* KsB = (const char*)Ks + kbo;
#pragma unroll
      for (int kk = 0; kk < 4; kk++) {
        const int cb = (kk * 64 + lg * 16) ^ swK;
        short8 k0 = *(const short8*)(KsB + lr * 256 + cb);
        short8 k1 = *(const short8*)(KsB + (16 + lr) * 256 + cb);
        s0 = __builtin_amdgcn_mfma_f32_16x16x32_bf16(qf[kk], k0, s0, 0, 0, 0);
        s1 = __builtin_amdgcn_mfma_f32_16x16x32_bf16(qf[kk], k1, s1, 0, 0, 0);
      }

      // ---- online softmax with defer-max (T13, THR=8) ----
      float v0a[4], v1a[4], pmax[4];
      float need = 0.f;
#pragma unroll
      for (int r = 0; r < 4; r++) {
        const int qrow = q0w + lg * 4 + r;
        float v0 = (kv0 + lr <= qrow) ? s0[r] * scale : -INFINITY;
        float v1 = (kv0 + 16 + lr <= qrow) ? s1[r] * scale : -INFINITY;
        float pm = fmaxf(v0, v1);
#pragma unroll
        for (int off = 1; off < 16; off <<= 1) pm = fmaxf(pm, __shfl_xor(pm, off));
        v0a[r] = v0; v1a[r] = v1; pmax[r] = pm;
        need = fmaxf(need, pm - mrow[r]);   // first iter: -(-inf) -> +inf -> slow path
      }
      float p0[4], p1[4];
      if (__all(need <= 8.f)) {
        // fast path: keep old max, skip alpha/rescale (P bounded by e^8)
#pragma unroll
        for (int r = 0; r < 4; r++) {
          p0[r] = __expf(v0a[r] - mrow[r]);
          p1[r] = __expf(v1a[r] - mrow[r]);
          float ps = p0[r] + p1[r];
#pragma unroll
          for (int off = 1; off < 16; off <<= 1) ps += __shfl_xor(ps, off);
          lsum[r] += ps;
        }
      } else {
        float al[4];
#pragma unroll
        for (int r = 0; r < 4; r++) {
          const float mnew = fmaxf(mrow[r], pmax[r]);
          al[r] = __expf(mrow[r] - mnew);    // first iter: exp(-inf)=0
          p0[r] = __expf(v0a[r] - mnew);
          p1[r] = __expf(v1a[r] - mnew);
          mrow[r] = mnew;
          float ps = p0[r] + p1[r];
#pragma unroll
          for (int off = 1; off < 16; off <<= 1) ps += __shfl_xor(ps, off);
          lsum[r] = lsum[r] * al[r] + ps;
        }
#pragma unroll
        for (int d0 = 0; d0 < 8; ++d0) {
          f32x4 tt = o[d0];
          tt[0] *= al[0]; tt[1] *= al[1]; tt[2] *= al[2]; tt[3] *= al[3];
          o[d0] = tt;
        }
      }

      // ---- P (C-layout) -> per-wave LDS tile in A-operand feed layout ----
#pragma unroll
      for (int r = 0; r < 4; r++) {
        Plw[(lg * 4 + r) * 32 + lr]      = f2bf(p0[r]);
        Plw[(lg * 4 + r) * 32 + 16 + lr] = f2bf(p1[r]);
      }
      // wave-local data: drain Pl writes; fence the scheduler (rule 18)
      asm volatile("s_waitcnt lgkmcnt(0)" ::: "memory");
      __builtin_amdgcn_sched_barrier(0);

      const short8 pa = *(const short8*)&Plw[lr * 32 + lk8];
#pragma unroll
      for (int d0 = 0; d0 < 8; ++d0) {
        const int d = d0 * 16 + lr;
        const int sw = ((d >> 1) & 3) ^ ((d >> 4) & 3);
        const short8 vb = *(const short8*)&Vt[vbo + d * 32 + ((lg ^ sw) << 3)];
        o[d0] = __builtin_amdgcn_mfma_f32_16x16x32_bf16(pa, vb, o[d0], 0, 0, 0);
      }
    }

    // ---- write next V tile into buf^1 (compiler waits vmcnt for nv0/nv1) ----
    if (havenext) {
      const int nvbo = vbo ^ 4096;
#pragma unroll
      for (int j = 0; j < 8; j++) {
        const int d = c16 + j;
        const int sw = ((d >> 1) & 3) ^ ((d >> 4) & 3);
        Vt[nvbo + d * 32 + (((vr >> 3) ^ sw) << 3) + (vr & 7)] = ((const unsigned short*)&nv0)[j];
      }
#pragma unroll
      for (int j = 0; j < 8; j++) {
        const int d = c16 + 8 + j;
        const int sw = ((d >> 1) & 3) ^ ((d >> 4) & 3);
        Vt[nvbo + d * 32 + (((vr >> 3) ^ sw) << 3) + (vr & 7)] = ((const unsigned short*)&nv1)[j];
      }
    }
  }

  // normalize + store ctx (bf16), layout [B,S,H*D]
#pragma unroll
  for (int d0 = 0; d0 < 8; ++d0) {
#pragma unroll
    for (int r = 0; r < 4; r++) {
      const float val = o[d0][r] / lsum[r];
      Ctx[base + (size_t)(q0w + lg * 4 + r) * E_ + d0 * 16 + lr] = f2bf(val);
    }
  }
}

// ---------------- launcher ----------------
extern "C" void kernel_launch(void* const* d_in, const int* in_sizes, int n_in,
                              void* d_out, int out_size, void* d_ws, size_t ws_size,
                              hipStream_t stream) {
  const float* x  = (const float*)d_in[0];
  // d_in[1] = causal_mask (tril) — implemented analytically
  const float* wq = (const float*)d_in[2];
  const float* bq = (const float*)d_in[3];
  const float* wk = (const float*)d_in[4];
  const float* bk = (const float*)d_in[5];
  const float* wv = (const float*)d_in[6];
  const float* bv = (const float*)d_in[7];
  const float* wo = (const float*)d_in[8];
  const float* bo = (const float*)d_in[9];
  float* out = (float*)d_out;

  char* ws = (char*)d_ws;
  const size_t MB = 1024 * 1024;
  unsigned short* xb  = (unsigned short*)(ws);             // 32 MB
  unsigned short* wqb = (unsigned short*)(ws + 32 * MB);   // 8 MB
  unsigned short* wkb = (unsigned short*)(ws + 40 * MB);   // 8 MB
  unsigned short* wvb = (unsigned short*)(ws + 48 * MB);   // 8 MB
  unsigned short* wob = (unsigned short*)(ws + 56 * MB);   // 8 MB
  unsigned short* Qb  = (unsigned short*)(ws + 64 * MB);   // 32 MB
  unsigned short* Kb  = (unsigned short*)(ws + 96 * MB);   // 32 MB
  unsigned short* Vb  = (unsigned short*)(ws + 128 * MB);  // 32 MB
  unsigned short* Cb  = (unsigned short*)(ws + 160 * MB);  // 32 MB -> 192 MB total

  const int nx4 = M_ * E_ / 4;   // x elements /4
  const int nw4 = E_ * E_ / 4;   // weight elements /4
  cast_bf16_kernel<<<nx4 / 256, 256, 0, stream>>>(x,  xb,  nx4);
  cast_bf16_kernel<<<nw4 / 256, 256, 0, stream>>>(wq, wqb, nw4);
  cast_bf16_kernel<<<nw4 / 256, 256, 0, stream>>>(wk, wkb, nw4);
  cast_bf16_kernel<<<nw4 / 256, 256, 0, stream>>>(wv, wvb, nw4);
  cast_bf16_kernel<<<nw4 / 256, 256, 0, stream>>>(wo, wob, nw4);

  dim3 gg(E_ / 128, M_ / 128);   // (16, 64)
  gemm_bt<unsigned short><<<gg, 256, 0, stream>>>(xb, wqb, bq, Qb, M_, E_, E_);
  gemm_bt<unsigned short><<<gg, 256, 0, stream>>>(xb, wkb, bk, Kb, M_, E_, E_);
  gemm_bt<unsigned short><<<gg, 256, 0, stream>>>(xb, wvb, bv, Vb, M_, E_, E_);

  flash_attn<<<dim3(S_ / 64, H_, B_), 256, 0, stream>>>(Qb, Kb, Vb, Cb);

  gemm_bt<float><<<gg, 256, 0, stream>>>(Cb, wob, bo, out, M_, E_, E_);
}

// Round 4
// 763.277 us; speedup vs baseline: 1.2993x; 1.2993x over previous
//
#include <hip/hip_runtime.h>
#include <hip/hip_bf16.h>

// Problem constants
#define B_ 4
#define S_ 2048
#define E_ 2048
#define H_ 16
#define D_ 128
#define M_ (B_*S_)   // 8192 rows

typedef __attribute__((ext_vector_type(8))) short short8;
typedef __attribute__((ext_vector_type(4))) float f32x4;

__device__ __forceinline__ unsigned short f2bf(float f) {
  union { __hip_bfloat16 h; unsigned short u; } c;
  c.h = __float2bfloat16(f);
  return c.u;
}

__device__ __forceinline__ void gld_lds16(const void* g, void* l) {
  __builtin_amdgcn_global_load_lds((const __attribute__((address_space(1))) void*)g,
                                   (__attribute__((address_space(3))) void*)l, 16, 0, 0);
}

// ---------------- fp32 -> bf16 cast (vectorized) ----------------
__global__ __launch_bounds__(256) void cast_bf16_kernel(const float* __restrict__ in,
                                                        unsigned short* __restrict__ out,
                                                        int n4) {
  int i = blockIdx.x * 256 + threadIdx.x;
  if (i >= n4) return;
  float4 v = ((const float4*)in)[i];
  ushort4 o;
  o.x = f2bf(v.x); o.y = f2bf(v.y); o.z = f2bf(v.z); o.w = f2bf(v.w);
  ((ushort4*)out)[i] = o;
}

// ---------------- GEMM: C[M,N] = A[M,K] @ W[N,K]^T + bias ----------------
// m97 structure: 128x128 tile, BK=32, 4 waves (2x2 of 64x64), global_load_lds w16.
template <typename OutT>
__global__ __launch_bounds__(256) void gemm_bt(const unsigned short* __restrict__ A,
                                               const unsigned short* __restrict__ W,
                                               const float* __restrict__ bias,
                                               OutT* __restrict__ C,
                                               int M, int N, int K) {
  __shared__ unsigned short As[128 * 32];
  __shared__ unsigned short Bs[128 * 32];
  const int tid  = threadIdx.x;
  const int lane = tid & 63;
  const int wid  = tid >> 6;
  const int m0 = blockIdx.y * 128;
  const int n0 = blockIdx.x * 128;
  const int wr = (wid >> 1) * 64;   // wave row offset in tile
  const int wc = (wid & 1) * 64;    // wave col offset in tile
  const int lr  = lane & 15;
  const int lk8 = (lane >> 4) * 8;

  f32x4 acc[4][4];
#pragma unroll
  for (int i = 0; i < 4; i++)
#pragma unroll
    for (int j = 0; j < 4; j++) acc[i][j] = (f32x4){0.f, 0.f, 0.f, 0.f};

  // staging: tile is 128 rows x 32 cols bf16 = 8192 B; 256 thr x 16 B = 4096 B/pass
  const int o0 = tid * 16;            // byte offset in tile, pass 0
  const int row0 = o0 >> 6, colb0 = o0 & 63;
  const int o1 = o0 + 4096;           // pass 1
  const int row1 = o1 >> 6, colb1 = o1 & 63;
  const int ldsb0 = wid * 1024;       // wave-uniform LDS byte base, pass 0
  const int ldsb1 = wid * 1024 + 4096;

  for (int kt = 0; kt < K; kt += 32) {
    gld_lds16(A + (size_t)(m0 + row0) * K + kt + (colb0 >> 1), (char*)As + ldsb0);
    gld_lds16(A + (size_t)(m0 + row1) * K + kt + (colb1 >> 1), (char*)As + ldsb1);
    gld_lds16(W + (size_t)(n0 + row0) * K + kt + (colb0 >> 1), (char*)Bs + ldsb0);
    gld_lds16(W + (size_t)(n0 + row1) * K + kt + (colb1 >> 1), (char*)Bs + ldsb1);
    __syncthreads();

    short8 af[4], bf[4];
#pragma unroll
    for (int i = 0; i < 4; i++) af[i] = *(const short8*)&As[(wr + i * 16 + lr) * 32 + lk8];
#pragma unroll
    for (int j = 0; j < 4; j++) bf[j] = *(const short8*)&Bs[(wc + j * 16 + lr) * 32 + lk8];
#pragma unroll
    for (int i = 0; i < 4; i++)
#pragma unroll
      for (int j = 0; j < 4; j++)
        acc[i][j] = __builtin_amdgcn_mfma_f32_16x16x32_bf16(af[i], bf[j], acc[i][j], 0, 0, 0);
    __syncthreads();
  }

  // epilogue: C/D layout col=lane&15, row=(lane>>4)*4+r  [m89-verified]
#pragma unroll
  for (int i = 0; i < 4; i++) {
    const int gm = m0 + wr + i * 16 + (lane >> 4) * 4;
#pragma unroll
    for (int j = 0; j < 4; j++) {
      const int gn = n0 + wc + j * 16 + lr;
      const float bv = bias[gn];
#pragma unroll
      for (int r = 0; r < 4; r++) {
        const float v = acc[i][j][r] + bv;
        if constexpr (sizeof(OutT) == 2)
          ((unsigned short*)C)[(size_t)(gm + r) * N + gn] = f2bf(v);
        else
          ((float*)C)[(size_t)(gm + r) * N + gn] = v;
      }
    }
  }
}

// ---------------- causal flash attention (folded, balanced grid) ----------------
// 4 waves (256 thr) per block; each wave owns 16 consecutive query rows
// (64-row q-tile). CAUSAL FOLD: block bx processes q-tile bx AND q-tile
// (31-bx), so every block does exactly 66 kv-steps -> perfect load balance,
// no drain tail (r1's OccupancyPercent 15.7% was the imbalance tail).
// Grid = 1024 blocks = steady 4 blocks/CU (LDS 20 KB -> 8 possible).
//
// Per kv-step (single-buffered, r1-verified layouts/math):
//   stage K (gld_lds, XOR-swizzle cb^=(row&7)<<4 on GLOBAL src, rule 21)
//   stage V (reg -> swizzled Vt ds_writes)
//   __syncthreads
//   QK^T -> online softmax (defer-max T13, THR=8) -> Pl (per-wave)
//   wave-local lgkmcnt(0)+sched_barrier (rule 18) -> PV MFMAs
//   __syncthreads
__global__ __launch_bounds__(256) void flash_attn(const unsigned short* __restrict__ Q,
                                                  const unsigned short* __restrict__ K,
                                                  const unsigned short* __restrict__ V,
                                                  unsigned short* __restrict__ Ctx) {
  __shared__ unsigned short Ks[32 * 128];   // 8 KB, swizzled K tile
  __shared__ unsigned short Vt[128 * 32];   // 8 KB, swizzled V^T tile
  __shared__ unsigned short Pl[4 * 16 * 32]; // 4 KB, per-wave P tiles

  const int tid  = threadIdx.x;
  const int lane = tid & 63;
  const int wid  = tid >> 6;
  const int lr  = lane & 15;
  const int lg  = lane >> 4;
  const int lk8 = lg * 8;
  const int h  = blockIdx.y;
  const int b  = blockIdx.z;
  const size_t base = ((size_t)b * S_) * E_ + (size_t)h * D_;
  const unsigned short* __restrict__ Kh = K + base;
  const unsigned short* __restrict__ Vh = V + base;
  unsigned short* Plw = Pl + wid * 512;

  // ---- K staging geometry (per 32x128 tile = 8192 B; 2 passes x 4096 B) ----
  const int oK0 = tid * 16;
  const int rK0 = oK0 >> 8;                 // rows 0..15
  const int cK0 = (oK0 & 255) ^ ((rK0 & 7) << 4);
  const int rK1 = (oK0 + 4096) >> 8;        // rows 16..31
  const int cK1 = (oK0 & 255) ^ ((rK1 & 7) << 4);
  const unsigned short* ksrc0 = Kh + (size_t)rK0 * E_ + (cK0 >> 1);
  const unsigned short* ksrc1 = Kh + (size_t)rK1 * E_ + (cK1 >> 1);
  char* kdst0 = (char*)Ks + wid * 1024;
  char* kdst1 = (char*)Ks + 4096 + wid * 1024;

  // ---- V staging geometry: thread loads 16 u16 of one kv row ----
  const int vr  = tid >> 3;                 // kv row 0..31
  const int c16 = (tid & 7) * 16;           // d base 0..112

  const float scale = 0.08838834764831845f;  // 1/sqrt(128)

#pragma unroll 1
  for (int half = 0; half < 2; ++half) {
    const int ti = half ? (31 - (int)blockIdx.x) : (int)blockIdx.x;
    const int qblk = ti * 64;               // q-tile base
    const int q0w  = qblk + wid * 16;       // this wave's q rows

    // ---- Q fragments: rows q0w+lr, feature k = kk*32 + lk8 .. +8 ----
    short8 qf[4];
#pragma unroll
    for (int kk = 0; kk < 4; kk++)
      qf[kk] = *(const short8*)&Q[base + (size_t)(q0w + lr) * E_ + kk * 32 + lk8];

    f32x4 o[8];
#pragma unroll
    for (int d0 = 0; d0 < 8; d0++) o[d0] = (f32x4){0.f, 0.f, 0.f, 0.f};
    float mrow[4] = {-INFINITY, -INFINITY, -INFINITY, -INFINITY};
    float lsum[4] = {0.f, 0.f, 0.f, 0.f};

    const int nt = (qblk >> 5) + 2;         // (qblk+64)/32 kv steps

    for (int t = 0; t < nt; ++t) {
      const int kv0 = t * 32;
      const size_t koff = (size_t)t * 32 * E_;

      // ---- stage K (async to LDS) + V (reg -> swizzled transpose) ----
      gld_lds16(ksrc0 + koff, kdst0);
      gld_lds16(ksrc1 + koff, kdst1);
      {
        short8 vv0 = *(const short8*)&Vh[koff + (size_t)vr * E_ + c16];
        short8 vv1 = *(const short8*)&Vh[koff + (size_t)vr * E_ + c16 + 8];
#pragma unroll
        for (int j = 0; j < 8; j++) {
          const int d = c16 + j;
          const int sw = ((d >> 1) & 3) ^ ((d >> 4) & 3);
          Vt[d * 32 + (((vr >> 3) ^ sw) << 3) + (vr & 7)] = ((const unsigned short*)&vv0)[j];
        }
#pragma unroll
        for (int j = 0; j < 8; j++) {
          const int d = c16 + 8 + j;
          const int sw = ((d >> 1) & 3) ^ ((d >> 4) & 3);
          Vt[d * 32 + (((vr >> 3) ^ sw) << 3) + (vr & 7)] = ((const unsigned short*)&vv1)[j];
        }
      }
      __syncthreads();   // staged (drains vmcnt for gld_lds + lgkm for ds_writes)

      if (kv0 < q0w + 16) {    // wave has unmasked kv cols this step
        // ---- S = Q K^T for two 16-col chunks (K from swizzled LDS) ----
        f32x4 s0 = (f32x4){0.f, 0.f, 0.f, 0.f};
        f32x4 s1 = (f32x4){0.f, 0.f, 0.f, 0.f};
        const int swK = (lr & 7) << 4;
#pragma unroll
        for (int kk = 0; kk < 4; kk++) {
          const int cb = (kk * 64 + lg * 16) ^ swK;
          short8 k0 = *(const short8*)((const char*)Ks + lr * 256 + cb);
          short8 k1 = *(const short8*)((const char*)Ks + (16 + lr) * 256 + cb);
          s0 = __builtin_amdgcn_mfma_f32_16x16x32_bf16(qf[kk], k0, s0, 0, 0, 0);
          s1 = __builtin_amdgcn_mfma_f32_16x16x32_bf16(qf[kk], k1, s1, 0, 0, 0);
        }

        // ---- online softmax with defer-max (T13, THR=8) ----
        float v0a[4], v1a[4], pmax[4];
        float need = 0.f;
#pragma unroll
        for (int r = 0; r < 4; r++) {
          const int qrow = q0w + lg * 4 + r;
          float v0 = (kv0 + lr <= qrow) ? s0[r] * scale : -INFINITY;
          float v1 = (kv0 + 16 + lr <= qrow) ? s1[r] * scale : -INFINITY;
          float pm = fmaxf(v0, v1);
#pragma unroll
          for (int off = 1; off < 16; off <<= 1) pm = fmaxf(pm, __shfl_xor(pm, off));
          v0a[r] = v0; v1a[r] = v1; pmax[r] = pm;
          need = fmaxf(need, pm - mrow[r]);  // first iter: +inf -> slow path
        }
        float p0[4], p1[4];
        if (__all(need <= 8.f)) {
          // fast path: keep old max, skip alpha/rescale (P bounded by e^8)
#pragma unroll
          for (int r = 0; r < 4; r++) {
            p0[r] = __expf(v0a[r] - mrow[r]);
            p1[r] = __expf(v1a[r] - mrow[r]);
            float ps = p0[r] + p1[r];
#pragma unroll
            for (int off = 1; off < 16; off <<= 1) ps += __shfl_xor(ps, off);
            lsum[r] += ps;
          }
        } else {
          float al[4];
#pragma unroll
          for (int r = 0; r < 4; r++) {
            const float mnew = fmaxf(mrow[r], pmax[r]);
            al[r] = __expf(mrow[r] - mnew);  // first iter: exp(-inf)=0
            p0[r] = __expf(v0a[r] - mnew);
            p1[r] = __expf(v1a[r] - mnew);
            mrow[r] = mnew;
            float ps = p0[r] + p1[r];
#pragma unroll
            for (int off = 1; off < 16; off <<= 1) ps += __shfl_xor(ps, off);
            lsum[r] = lsum[r] * al[r] + ps;
          }
#pragma unroll
          for (int d0 = 0; d0 < 8; ++d0) {
            f32x4 tt = o[d0];
            tt[0] *= al[0]; tt[1] *= al[1]; tt[2] *= al[2]; tt[3] *= al[3];
            o[d0] = tt;
          }
        }

        // ---- P (C-layout) -> per-wave LDS tile in A-operand feed layout ----
#pragma unroll
        for (int r = 0; r < 4; r++) {
          Plw[(lg * 4 + r) * 32 + lr]      = f2bf(p0[r]);
          Plw[(lg * 4 + r) * 32 + 16 + lr] = f2bf(p1[r]);
        }
        // wave-local data only: drain Pl writes; fence scheduler (rule 18)
        asm volatile("s_waitcnt lgkmcnt(0)" ::: "memory");
        __builtin_amdgcn_sched_barrier(0);

        const short8 pa = *(const short8*)&Plw[lr * 32 + lk8];
#pragma unroll
        for (int d0 = 0; d0 < 8; ++d0) {
          const int d = d0 * 16 + lr;
          const int sw = ((d >> 1) & 3) ^ ((d >> 4) & 3);
          const short8 vb = *(const short8*)&Vt[d * 32 + ((lg ^ sw) << 3)];
          o[d0] = __builtin_amdgcn_mfma_f32_16x16x32_bf16(pa, vb, o[d0], 0, 0, 0);
        }
      }
      __syncthreads();   // all Ks/Vt reads done before next stage
    }

    // ---- normalize + store ctx (bf16) for this q-tile ----
#pragma unroll
    for (int d0 = 0; d0 < 8; ++d0) {
#pragma unroll
      for (int r = 0; r < 4; r++) {
        const float val = o[d0][r] / lsum[r];
        Ctx[base + (size_t)(q0w + lg * 4 + r) * E_ + d0 * 16 + lr] = f2bf(val);
      }
    }
  }
}

// ---------------- launcher ----------------
extern "C" void kernel_launch(void* const* d_in, const int* in_sizes, int n_in,
                              void* d_out, int out_size, void* d_ws, size_t ws_size,
                              hipStream_t stream) {
  const float* x  = (const float*)d_in[0];
  // d_in[1] = causal_mask (tril) — implemented analytically
  const float* wq = (const float*)d_in[2];
  const float* bq = (const float*)d_in[3];
  const float* wk = (const float*)d_in[4];
  const float* bk = (const float*)d_in[5];
  const float* wv = (const float*)d_in[6];
  const float* bv = (const float*)d_in[7];
  const float* wo = (const float*)d_in[8];
  const float* bo = (const float*)d_in[9];
  float* out = (float*)d_out;

  char* ws = (char*)d_ws;
  const size_t MB = 1024 * 1024;
  unsigned short* xb  = (unsigned short*)(ws);             // 32 MB
  unsigned short* wqb = (unsigned short*)(ws + 32 * MB);   // 8 MB
  unsigned short* wkb = (unsigned short*)(ws + 40 * MB);   // 8 MB
  unsigned short* wvb = (unsigned short*)(ws + 48 * MB);   // 8 MB
  unsigned short* wob = (unsigned short*)(ws + 56 * MB);   // 8 MB
  unsigned short* Qb  = (unsigned short*)(ws + 64 * MB);   // 32 MB
  unsigned short* Kb  = (unsigned short*)(ws + 96 * MB);   // 32 MB
  unsigned short* Vb  = (unsigned short*)(ws + 128 * MB);  // 32 MB
  unsigned short* Cb  = (unsigned short*)(ws + 160 * MB);  // 32 MB -> 192 MB total

  const int nx4 = M_ * E_ / 4;   // x elements /4
  const int nw4 = E_ * E_ / 4;   // weight elements /4
  cast_bf16_kernel<<<nx4 / 256, 256, 0, stream>>>(x,  xb,  nx4);
  cast_bf16_kernel<<<nw4 / 256, 256, 0, stream>>>(wq, wqb, nw4);
  cast_bf16_kernel<<<nw4 / 256, 256, 0, stream>>>(wk, wkb, nw4);
  cast_bf16_kernel<<<nw4 / 256, 256, 0, stream>>>(wv, wvb, nw4);
  cast_bf16_kernel<<<nw4 / 256, 256, 0, stream>>>(wo, wob, nw4);

  dim3 gg(E_ / 128, M_ / 128);   // (16, 64)
  gemm_bt<unsigned short><<<gg, 256, 0, stream>>>(xb, wqb, bq, Qb, M_, E_, E_);
  gemm_bt<unsigned short><<<gg, 256, 0, stream>>>(xb, wkb, bk, Kb, M_, E_, E_);
  gemm_bt<unsigned short><<<gg, 256, 0, stream>>>(xb, wvb, bv, Vb, M_, E_, E_);

  // folded causal grid: block bx handles q-tiles bx and 31-bx (66 steps each)
  flash_attn<<<dim3(S_ / 64 / 2, H_, B_), 256, 0, stream>>>(Qb, Kb, Vb, Cb);

  gemm_bt<float><<<gg, 256, 0, stream>>>(Cb, wob, bo, out, M_, E_, E_);
}

// Round 5
// 683.268 us; speedup vs baseline: 1.4514x; 1.1171x over previous
//
#include <hip/hip_runtime.h>
#include <hip/hip_bf16.h>

// Problem constants
#define B_ 4
#define S_ 2048
#define E_ 2048
#define H_ 16
#define D_ 128
#define M_ (B_*S_)   // 8192 rows

typedef __attribute__((ext_vector_type(8))) short short8;
typedef __attribute__((ext_vector_type(4))) float f32x4;

__device__ __forceinline__ unsigned short f2bf(float f) {
  union { __hip_bfloat16 h; unsigned short u; } c;
  c.h = __float2bfloat16(f);
  return c.u;
}

__device__ __forceinline__ void gld_lds16(const void* g, void* l) {
  __builtin_amdgcn_global_load_lds((const __attribute__((address_space(1))) void*)g,
                                   (__attribute__((address_space(3))) void*)l, 16, 0, 0);
}

// ---------------- fp32 -> bf16 cast (vectorized) ----------------
__global__ __launch_bounds__(256) void cast_bf16_kernel(const float* __restrict__ in,
                                                        unsigned short* __restrict__ out,
                                                        int n4) {
  int i = blockIdx.x * 256 + threadIdx.x;
  if (i >= n4) return;
  float4 v = ((const float4*)in)[i];
  ushort4 o;
  o.x = f2bf(v.x); o.y = f2bf(v.y); o.z = f2bf(v.z); o.w = f2bf(v.w);
  ((ushort4*)out)[i] = o;
}

// ---------------- GEMM: C[M,N] = A[M,K] @ W[N,K]^T + bias ----------------
// m97 structure: 128x128 tile, BK=32, 4 waves (2x2 of 64x64), global_load_lds w16.
template <typename OutT>
__global__ __launch_bounds__(256) void gemm_bt(const unsigned short* __restrict__ A,
                                               const unsigned short* __restrict__ W,
                                               const float* __restrict__ bias,
                                               OutT* __restrict__ C,
                                               int M, int N, int K) {
  __shared__ unsigned short As[128 * 32];
  __shared__ unsigned short Bs[128 * 32];
  const int tid  = threadIdx.x;
  const int lane = tid & 63;
  const int wid  = tid >> 6;
  const int m0 = blockIdx.y * 128;
  const int n0 = blockIdx.x * 128;
  const int wr = (wid >> 1) * 64;   // wave row offset in tile
  const int wc = (wid & 1) * 64;    // wave col offset in tile
  const int lr  = lane & 15;
  const int lk8 = (lane >> 4) * 8;

  f32x4 acc[4][4];
#pragma unroll
  for (int i = 0; i < 4; i++)
#pragma unroll
    for (int j = 0; j < 4; j++) acc[i][j] = (f32x4){0.f, 0.f, 0.f, 0.f};

  // staging: tile is 128 rows x 32 cols bf16 = 8192 B; 256 thr x 16 B = 4096 B/pass
  const int o0 = tid * 16;            // byte offset in tile, pass 0
  const int row0 = o0 >> 6, colb0 = o0 & 63;
  const int o1 = o0 + 4096;           // pass 1
  const int row1 = o1 >> 6, colb1 = o1 & 63;
  const int ldsb0 = wid * 1024;       // wave-uniform LDS byte base, pass 0
  const int ldsb1 = wid * 1024 + 4096;

  for (int kt = 0; kt < K; kt += 32) {
    gld_lds16(A + (size_t)(m0 + row0) * K + kt + (colb0 >> 1), (char*)As + ldsb0);
    gld_lds16(A + (size_t)(m0 + row1) * K + kt + (colb1 >> 1), (char*)As + ldsb1);
    gld_lds16(W + (size_t)(n0 + row0) * K + kt + (colb0 >> 1), (char*)Bs + ldsb0);
    gld_lds16(W + (size_t)(n0 + row1) * K + kt + (colb1 >> 1), (char*)Bs + ldsb1);
    __syncthreads();

    short8 af[4], bf[4];
#pragma unroll
    for (int i = 0; i < 4; i++) af[i] = *(const short8*)&As[(wr + i * 16 + lr) * 32 + lk8];
#pragma unroll
    for (int j = 0; j < 4; j++) bf[j] = *(const short8*)&Bs[(wc + j * 16 + lr) * 32 + lk8];
#pragma unroll
    for (int i = 0; i < 4; i++)
#pragma unroll
      for (int j = 0; j < 4; j++)
        acc[i][j] = __builtin_amdgcn_mfma_f32_16x16x32_bf16(af[i], bf[j], acc[i][j], 0, 0, 0);
    __syncthreads();
  }

  // epilogue: C/D layout col=lane&15, row=(lane>>4)*4+r  [m89-verified]
#pragma unroll
  for (int i = 0; i < 4; i++) {
    const int gm = m0 + wr + i * 16 + (lane >> 4) * 4;
#pragma unroll
    for (int j = 0; j < 4; j++) {
      const int gn = n0 + wc + j * 16 + lr;
      const float bv = bias[gn];
#pragma unroll
      for (int r = 0; r < 4; r++) {
        const float v = acc[i][j][r] + bv;
        if constexpr (sizeof(OutT) == 2)
          ((unsigned short*)C)[(size_t)(gm + r) * N + gn] = f2bf(v);
        else
          ((float*)C)[(size_t)(gm + r) * N + gn] = v;
      }
    }
  }
}

// ---------------- causal flash attention (folded grid, swapped operands) ----------------
// 4 waves (256 thr) per block; wave owns 16 q rows; block handles q-tiles
// bx and 31-bx (66 kv-steps each -> perfect balance, r4-verified).
//
// SWAPPED-OPERAND structure (A-frag of X == B-frag of X^T, same lane regs):
//   S^T = mfma(kf, qf): lane holds S[kv = lg*4+r (+16)][qrow = lr]
//     -> row stats (m,l) are ONE SCALAR per lane; row-reduce = 7 in-lane
//        fmax/add + 2 shuffles (xor 16, 32) instead of 32 shuffles/step.
//   O^T = mfma(vb, pb): vb = A-frag of V^T (identical Vt read to r4-verified),
//     pb = B-frag of P from per-wave feed layout
//       Plf[(kv>>3)*128 + q*8 + (kv&7)]
//     write: two packed 8B ds_write per lane (conflict-free by construction);
//     read: contiguous 16B per lane.
//   O^T lane layout: o[d0][r] = O[qrow=lr][d = d0*16 + lg*4 + r]
//     -> alpha-rescale & 1/lsum scalar; stores packed ushort4.
// Staging (r1/r4-verified): K via gld_lds w/ XOR-swizzle on GLOBAL src (rule 21);
// V reg->swizzled Vt ds_writes. Defer-max (T13, THR=8).
__global__ __launch_bounds__(256) void flash_attn(const unsigned short* __restrict__ Q,
                                                  const unsigned short* __restrict__ K,
                                                  const unsigned short* __restrict__ V,
                                                  unsigned short* __restrict__ Ctx) {
  __shared__ unsigned short Ks[32 * 128];    // 8 KB, swizzled K tile
  __shared__ unsigned short Vt[128 * 32];    // 8 KB, swizzled V^T tile
  __shared__ unsigned short Pl[4 * 512];     // 4 KB, per-wave P feed tiles

  const int tid  = threadIdx.x;
  const int lane = tid & 63;
  const int wid  = tid >> 6;
  const int lr  = lane & 15;
  const int lg  = lane >> 4;
  const int lk8 = lg * 8;
  const int h  = blockIdx.y;
  const int b  = blockIdx.z;
  const size_t base = ((size_t)b * S_) * E_ + (size_t)h * D_;
  const unsigned short* __restrict__ Kh = K + base;
  const unsigned short* __restrict__ Vh = V + base;
  unsigned short* Plf = Pl + wid * 512;

  // ---- K staging geometry (per 32x128 tile = 8192 B; 2 passes x 4096 B) ----
  const int oK0 = tid * 16;
  const int rK0 = oK0 >> 8;                 // rows 0..15
  const int cK0 = (oK0 & 255) ^ ((rK0 & 7) << 4);
  const int rK1 = (oK0 + 4096) >> 8;        // rows 16..31
  const int cK1 = (oK0 & 255) ^ ((rK1 & 7) << 4);
  const unsigned short* ksrc0 = Kh + (size_t)rK0 * E_ + (cK0 >> 1);
  const unsigned short* ksrc1 = Kh + (size_t)rK1 * E_ + (cK1 >> 1);
  char* kdst0 = (char*)Ks + wid * 1024;
  char* kdst1 = (char*)Ks + 4096 + wid * 1024;

  // ---- V staging geometry: thread loads 16 u16 of one kv row ----
  const int vr  = tid >> 3;                 // kv row 0..31
  const int c16 = (tid & 7) * 16;           // d base 0..112

  // ---- P feed addresses (per-lane, constant across steps) ----
  const int plw0 = (lg >> 1) * 128 + lr * 8 + (lg & 1) * 4;  // p0 pack (4 u16)
  // p1 pack at plw0 + 256; B-frag read at lg*128 + lr*8 (8 u16, 16B)
  const int plrd = lg * 128 + lr * 8;

  const float scale = 0.08838834764831845f;  // 1/sqrt(128)

#pragma unroll 1
  for (int half = 0; half < 2; ++half) {
    const int ti = half ? (31 - (int)blockIdx.x) : (int)blockIdx.x;
    const int qblk = ti * 64;               // q-tile base
    const int q0w  = qblk + wid * 16;       // this wave's q rows
    const int qrow = q0w + lr;              // this lane's softmax row

    // ---- Q fragments: rows q0w+lr, feature k = kk*32 + lk8 .. +8 ----
    short8 qf[4];
#pragma unroll
    for (int kk = 0; kk < 4; kk++)
      qf[kk] = *(const short8*)&Q[base + (size_t)(q0w + lr) * E_ + kk * 32 + lk8];

    f32x4 o[8];
#pragma unroll
    for (int d0 = 0; d0 < 8; d0++) o[d0] = (f32x4){0.f, 0.f, 0.f, 0.f};
    float mrow = -INFINITY;
    float lsum = 0.f;

    const int nt = (qblk >> 5) + 2;         // (qblk+64)/32 kv steps

    for (int t = 0; t < nt; ++t) {
      const int kv0 = t * 32;
      const size_t koff = (size_t)t * 32 * E_;

      // ---- stage K (async to LDS) + V (reg -> swizzled transpose) ----
      gld_lds16(ksrc0 + koff, kdst0);
      gld_lds16(ksrc1 + koff, kdst1);
      {
        short8 vv0 = *(const short8*)&Vh[koff + (size_t)vr * E_ + c16];
        short8 vv1 = *(const short8*)&Vh[koff + (size_t)vr * E_ + c16 + 8];
#pragma unroll
        for (int j = 0; j < 8; j++) {
          const int d = c16 + j;
          const int sw = ((d >> 1) & 3) ^ ((d >> 4) & 3);
          Vt[d * 32 + (((vr >> 3) ^ sw) << 3) + (vr & 7)] = ((const unsigned short*)&vv0)[j];
        }
#pragma unroll
        for (int j = 0; j < 8; j++) {
          const int d = c16 + 8 + j;
          const int sw = ((d >> 1) & 3) ^ ((d >> 4) & 3);
          Vt[d * 32 + (((vr >> 3) ^ sw) << 3) + (vr & 7)] = ((const unsigned short*)&vv1)[j];
        }
      }
      __syncthreads();   // staged (drains vmcnt for gld_lds + lgkm for ds_writes)

      if (kv0 < q0w + 16) {    // wave has unmasked kv cols this step
        // ---- S^T = K Q^T : lane holds S[kv0 + lg*4+r (+16)][qrow] ----
        f32x4 s0 = (f32x4){0.f, 0.f, 0.f, 0.f};
        f32x4 s1 = (f32x4){0.f, 0.f, 0.f, 0.f};
        const int swK = (lr & 7) << 4;
#pragma unroll
        for (int kk = 0; kk < 4; kk++) {
          const int cb = (kk * 64 + lg * 16) ^ swK;
          short8 k0 = *(const short8*)((const char*)Ks + lr * 256 + cb);
          short8 k1 = *(const short8*)((const char*)Ks + (16 + lr) * 256 + cb);
          s0 = __builtin_amdgcn_mfma_f32_16x16x32_bf16(k0, qf[kk], s0, 0, 0, 0);
          s1 = __builtin_amdgcn_mfma_f32_16x16x32_bf16(k1, qf[kk], s1, 0, 0, 0);
        }

        // ---- masked scores; row-reduce in-lane + 2 shuffles ----
        const int kvb0 = kv0 + lg * 4;       // s0 kv base
        float v0[4], v1[4];
#pragma unroll
        for (int r = 0; r < 4; r++) {
          v0[r] = (kvb0 + r      <= qrow) ? s0[r] * scale : -INFINITY;
          v1[r] = (kvb0 + 16 + r <= qrow) ? s1[r] * scale : -INFINITY;
        }
        float pm = fmaxf(fmaxf(fmaxf(v0[0], v0[1]), fmaxf(v0[2], v0[3])),
                         fmaxf(fmaxf(v1[0], v1[1]), fmaxf(v1[2], v1[3])));
        pm = fmaxf(pm, __shfl_xor(pm, 16));
        pm = fmaxf(pm, __shfl_xor(pm, 32));

        // ---- online softmax with defer-max (T13, THR=8) ----
        float p0[4], p1[4];
        const float need = pm - mrow;        // first iter: +inf -> slow path
        if (__all(need <= 8.f)) {
          // fast path: keep old max, skip alpha/rescale (P bounded by e^8)
#pragma unroll
          for (int r = 0; r < 4; r++) {
            p0[r] = __expf(v0[r] - mrow);
            p1[r] = __expf(v1[r] - mrow);
          }
          float ps = (p0[0] + p0[1]) + (p0[2] + p0[3])
                   + (p1[0] + p1[1]) + (p1[2] + p1[3]);
          ps += __shfl_xor(ps, 16);
          ps += __shfl_xor(ps, 32);
          lsum += ps;
        } else {
          const float mnew = fmaxf(mrow, pm);
          const float al = __expf(mrow - mnew);   // first iter: exp(-inf)=0
#pragma unroll
          for (int r = 0; r < 4; r++) {
            p0[r] = __expf(v0[r] - mnew);
            p1[r] = __expf(v1[r] - mnew);
          }
          mrow = mnew;
          float ps = (p0[0] + p0[1]) + (p0[2] + p0[3])
                   + (p1[0] + p1[1]) + (p1[2] + p1[3]);
          ps += __shfl_xor(ps, 16);
          ps += __shfl_xor(ps, 32);
          lsum = lsum * al + ps;
#pragma unroll
          for (int d0 = 0; d0 < 8; ++d0) {
            f32x4 tt = o[d0];
            tt[0] *= al; tt[1] *= al; tt[2] *= al; tt[3] *= al;
            o[d0] = tt;
          }
        }

        // ---- P -> per-wave feed tile (two packed 8B writes) ----
        ushort4 w0, w1;
        w0.x = f2bf(p0[0]); w0.y = f2bf(p0[1]); w0.z = f2bf(p0[2]); w0.w = f2bf(p0[3]);
        w1.x = f2bf(p1[0]); w1.y = f2bf(p1[1]); w1.z = f2bf(p1[2]); w1.w = f2bf(p1[3]);
        *(ushort4*)&Plf[plw0]       = w0;
        *(ushort4*)&Plf[plw0 + 256] = w1;
        // wave-local data only: drain Plf writes; fence scheduler (rule 18)
        asm volatile("s_waitcnt lgkmcnt(0)" ::: "memory");
        __builtin_amdgcn_sched_barrier(0);

        // ---- O^T += V^T P : vb = A-frag of V^T (r4-verified read) ----
        const short8 pb = *(const short8*)&Plf[plrd];
#pragma unroll
        for (int d0 = 0; d0 < 8; ++d0) {
          const int d = d0 * 16 + lr;
          const int sw = ((d >> 1) & 3) ^ ((d >> 4) & 3);
          const short8 vb = *(const short8*)&Vt[d * 32 + ((lg ^ sw) << 3)];
          o[d0] = __builtin_amdgcn_mfma_f32_16x16x32_bf16(vb, pb, o[d0], 0, 0, 0);
        }
      }
      __syncthreads();   // all Ks/Vt reads done before next stage
    }

    // ---- normalize + store ctx (bf16): o[d0][r] = O[qrow][d0*16+lg*4+r] ----
    const float inv = 1.0f / lsum;
    unsigned short* crow = Ctx + base + (size_t)qrow * E_ + lg * 4;
#pragma unroll
    for (int d0 = 0; d0 < 8; ++d0) {
      ushort4 st;
      st.x = f2bf(o[d0][0] * inv);
      st.y = f2bf(o[d0][1] * inv);
      st.z = f2bf(o[d0][2] * inv);
      st.w = f2bf(o[d0][3] * inv);
      *(ushort4*)&crow[d0 * 16] = st;
    }
  }
}

// ---------------- launcher ----------------
extern "C" void kernel_launch(void* const* d_in, const int* in_sizes, int n_in,
                              void* d_out, int out_size, void* d_ws, size_t ws_size,
                              hipStream_t stream) {
  const float* x  = (const float*)d_in[0];
  // d_in[1] = causal_mask (tril) — implemented analytically
  const float* wq = (const float*)d_in[2];
  const float* bq = (const float*)d_in[3];
  const float* wk = (const float*)d_in[4];
  const float* bk = (const float*)d_in[5];
  const float* wv = (const float*)d_in[6];
  const float* bv = (const float*)d_in[7];
  const float* wo = (const float*)d_in[8];
  const float* bo = (const float*)d_in[9];
  float* out = (float*)d_out;

  char* ws = (char*)d_ws;
  const size_t MB = 1024 * 1024;
  unsigned short* xb  = (unsigned short*)(ws);             // 32 MB
  unsigned short* wqb = (unsigned short*)(ws + 32 * MB);   // 8 MB
  unsigned short* wkb = (unsigned short*)(ws + 40 * MB);   // 8 MB
  unsigned short* wvb = (unsigned short*)(ws + 48 * MB);   // 8 MB
  unsigned short* wob = (unsigned short*)(ws + 56 * MB);   // 8 MB
  unsigned short* Qb  = (unsigned short*)(ws + 64 * MB);   // 32 MB
  unsigned short* Kb  = (unsigned short*)(ws + 96 * MB);   // 32 MB
  unsigned short* Vb  = (unsigned short*)(ws + 128 * MB);  // 32 MB
  unsigned short* Cb  = (unsigned short*)(ws + 160 * MB);  // 32 MB -> 192 MB total

  const int nx4 = M_ * E_ / 4;   // x elements /4
  const int nw4 = E_ * E_ / 4;   // weight elements /4
  cast_bf16_kernel<<<nx4 / 256, 256, 0, stream>>>(x,  xb,  nx4);
  cast_bf16_kernel<<<nw4 / 256, 256, 0, stream>>>(wq, wqb, nw4);
  cast_bf16_kernel<<<nw4 / 256, 256, 0, stream>>>(wk, wkb, nw4);
  cast_bf16_kernel<<<nw4 / 256, 256, 0, stream>>>(wv, wvb, nw4);
  cast_bf16_kernel<<<nw4 / 256, 256, 0, stream>>>(wo, wob, nw4);

  dim3 gg(E_ / 128, M_ / 128);   // (16, 64)
  gemm_bt<unsigned short><<<gg, 256, 0, stream>>>(xb, wqb, bq, Qb, M_, E_, E_);
  gemm_bt<unsigned short><<<gg, 256, 0, stream>>>(xb, wkb, bk, Kb, M_, E_, E_);
  gemm_bt<unsigned short><<<gg, 256, 0, stream>>>(xb, wvb, bv, Vb, M_, E_, E_);

  // folded causal grid: block bx handles q-tiles bx and 31-bx (66 steps each)
  flash_attn<<<dim3(S_ / 64 / 2, H_, B_), 256, 0, stream>>>(Qb, Kb, Vb, Cb);

  gemm_bt<float><<<gg, 256, 0, stream>>>(Cb, wob, bo, out, M_, E_, E_);
}